// Round 1
// baseline (138.564 us; speedup 1.0000x reference)
//
#include <hip/hip_runtime.h>
#include <hip/hip_bf16.h>

// Problem constants
#define N_PAIRS   64000
#define N_ATOMS   16000
#define N_FEAT    8
#define N_HIDDEN  100
// Padded dims
#define KP        128     // K (=100) padded to 128 for 4x mfma 16x16x32
#define SU        912     // U row stride: 57 n-tiles * 16 (covers 900 used cols)

typedef __attribute__((ext_vector_type(8))) short bf16x8_t;   // 8 bf16 = 4 VGPRs
typedef __attribute__((ext_vector_type(4))) float f32x4_t;

// ---- prep: atom_features fp32 (16000x100) -> bf16 (16000x128, zero-padded K)
__global__ __launch_bounds__(256) void prep_afb(const float* __restrict__ af,
                                                __hip_bfloat16* __restrict__ afb) {
    int id  = blockIdx.x * 256 + threadIdx.x;      // < 16000*128
    int row = id >> 7;
    int k   = id & 127;
    float v = (k < N_HIDDEN) ? af[row * N_HIDDEN + k] : 0.f;
    afb[id] = __float2bfloat16(v);
}

// ---- prep: Wt[c][k] with c = f*100+i (c<800), bias block c=800..899, zero pad
__global__ __launch_bounds__(256) void prep_wtb(const float* __restrict__ W,
                                                const float* __restrict__ b,
                                                __hip_bfloat16* __restrict__ wtb) {
    int id = blockIdx.x * 256 + threadIdx.x;       // < 912*128
    int c  = id >> 7;
    int k  = id & 127;
    float v = 0.f;
    if (k < N_HIDDEN) {
        if (c < N_FEAT * N_HIDDEN) {
            int f = c / N_HIDDEN;
            int i = c - f * N_HIDDEN;
            v = W[f * (N_HIDDEN * N_HIDDEN) + i * N_HIDDEN + k];
        } else if (c < (N_FEAT + 1) * N_HIDDEN) {
            int i = c - N_FEAT * N_HIDDEN;
            v = b[i * N_HIDDEN + k];
        }
    }
    wtb[id] = __float2bfloat16(v);
}

// ---- GEMM: U[a][c] = sum_k afb[a][k] * wtb[c][k], bf16 MFMA, U stored bf16
// grid.x = 250 (each block: 4 waves = 64 rows), grid.y = 3 (19 n-tiles each)
__global__ __launch_bounds__(256) void gemm_u(const __hip_bfloat16* __restrict__ afb,
                                              const __hip_bfloat16* __restrict__ wtb,
                                              __hip_bfloat16* __restrict__ u) {
    int wave = threadIdx.x >> 6;
    int lane = threadIdx.x & 63;
    int quad = lane >> 4;
    int l15  = lane & 15;
    int m0   = (blockIdx.x * 4 + wave) * 16;       // row tile base, < 16000

    // A fragments: lane holds A[m=lane&15][k=quad*8+j], 16B contiguous loads
    const __hip_bfloat16* ap = afb + (m0 + l15) * KP + quad * 8;
    bf16x8_t a0 = *(const bf16x8_t*)(ap);
    bf16x8_t a1 = *(const bf16x8_t*)(ap + 32);
    bf16x8_t a2 = *(const bf16x8_t*)(ap + 64);
    bf16x8_t a3 = *(const bf16x8_t*)(ap + 96);

    int nt0 = blockIdx.y * 19;
    for (int nt = nt0; nt < nt0 + 19; ++nt) {
        int c = nt * 16 + l15;
        // B fragments: lane holds B[k=quad*8+j][n=lane&15] = wtb[n][k]
        const __hip_bfloat16* bp = wtb + c * KP + quad * 8;
        bf16x8_t b0 = *(const bf16x8_t*)(bp);
        bf16x8_t b1 = *(const bf16x8_t*)(bp + 32);
        bf16x8_t b2 = *(const bf16x8_t*)(bp + 64);
        bf16x8_t b3 = *(const bf16x8_t*)(bp + 96);
        f32x4_t acc = {0.f, 0.f, 0.f, 0.f};
        acc = __builtin_amdgcn_mfma_f32_16x16x32_bf16(a0, b0, acc, 0, 0, 0);
        acc = __builtin_amdgcn_mfma_f32_16x16x32_bf16(a1, b1, acc, 0, 0, 0);
        acc = __builtin_amdgcn_mfma_f32_16x16x32_bf16(a2, b2, acc, 0, 0, 0);
        acc = __builtin_amdgcn_mfma_f32_16x16x32_bf16(a3, b3, acc, 0, 0, 0);
        // D layout: col = lane&15, row = quad*4 + r
#pragma unroll
        for (int r = 0; r < 4; ++r) {
            int rr = m0 + quad * 4 + r;
            u[rr * SU + c] = __float2bfloat16(acc[r]);
        }
    }
}

// ---- edge kernel: msg[e,i] = sum_f pf[e,f]*U[src][f*100+i] + U[src][800+i]
//      atomicAdd into out[dest][i]. 128 threads per edge.
__global__ __launch_bounds__(256) void edge_kernel(const float* __restrict__ pf,
                                                   const int* __restrict__ a2p,
                                                   const __hip_bfloat16* __restrict__ u,
                                                   float* __restrict__ out) {
    int gid = blockIdx.x * 256 + threadIdx.x;
    int e = gid >> 7;          // wave-uniform (128 threads per edge)
    int i = gid & 127;
    if (i >= N_HIDDEN) return;
    int dest = a2p[e * 2];
    int src  = a2p[e * 2 + 1];
    dest = __builtin_amdgcn_readfirstlane(dest);   // uniform within wave
    src  = __builtin_amdgcn_readfirstlane(src);
    const __hip_bfloat16* ur = u + src * SU;
    const float* pfe = pf + e * N_FEAT;
    float acc = __bfloat162float(ur[N_FEAT * N_HIDDEN + i]);   // bias block
#pragma unroll
    for (int f = 0; f < N_FEAT; ++f)
        acc += pfe[f] * __bfloat162float(ur[f * N_HIDDEN + i]);
    atomicAdd(&out[dest * N_HIDDEN + i], acc);
}

extern "C" void kernel_launch(void* const* d_in, const int* in_sizes, int n_in,
                              void* d_out, int out_size, void* d_ws, size_t ws_size,
                              hipStream_t stream) {
    const float* pf  = (const float*)d_in[0];   // (64000, 8)
    const float* af  = (const float*)d_in[1];   // (16000, 100)
    const int*   a2p = (const int*)d_in[2];     // (64000, 2)
    const float* W   = (const float*)d_in[3];   // (8, 10000)
    const float* b   = (const float*)d_in[4];   // (10000,)
    float* out = (float*)d_out;                 // (16000, 100) fp32

    char* ws = (char*)d_ws;
    __hip_bfloat16* afb = (__hip_bfloat16*)ws;                       // 16000*128*2 = 4,096,000 B
    __hip_bfloat16* wtb = (__hip_bfloat16*)(ws + 4096000);           //   912*128*2 =   233,472 B
    __hip_bfloat16* u   = (__hip_bfloat16*)(ws + 4096000 + 233472);  // 16000*912*2 = 29,184,000 B

    hipMemsetAsync(d_out, 0, (size_t)out_size * sizeof(float), stream);
    prep_afb<<<(N_ATOMS * KP) / 256, 256, 0, stream>>>(af, afb);
    prep_wtb<<<(SU * KP) / 256, 256, 0, stream>>>(W, b, wtb);
    gemm_u<<<dim3(N_ATOMS / 64, 3), 256, 0, stream>>>(afb, wtb, u);
    edge_kernel<<<(N_PAIRS * 128) / 256, 256, 0, stream>>>(pf, a2p, u, out);
}

// Round 2
// 133.079 us; speedup vs baseline: 1.0412x; 1.0412x over previous
//
#include <hip/hip_runtime.h>
#include <hip/hip_bf16.h>

// Problem constants
#define N_PAIRS   64000
#define N_ATOMS   16000
#define N_FEAT    8
#define N_HIDDEN  100
// Padded dims
#define KP        128     // K (=100) padded to 128 for 4x mfma 16x16x32
#define SU        912     // U row stride: 57 n-tiles * 16 (covers 900 used cols)
#define MAX_DEG   64      // bucket capacity per dest (uniform random, avg deg 4)

typedef __attribute__((ext_vector_type(8))) short bf16x8_t;   // 8 bf16 = 4 VGPRs
typedef __attribute__((ext_vector_type(4))) float f32x4_t;

// ---- prep: atom_features fp32 (16000x100) -> bf16 (16000x128, zero-padded K)
__global__ __launch_bounds__(256) void prep_afb(const float* __restrict__ af,
                                                __hip_bfloat16* __restrict__ afb) {
    int id  = blockIdx.x * 256 + threadIdx.x;      // < 16000*128
    int row = id >> 7;
    int k   = id & 127;
    float v = (k < N_HIDDEN) ? af[row * N_HIDDEN + k] : 0.f;
    afb[id] = __float2bfloat16(v);
}

// ---- prep: Wt[c][k] with c = f*100+i (c<800), bias block c=800..899, zero pad
__global__ __launch_bounds__(256) void prep_wtb(const float* __restrict__ W,
                                                const float* __restrict__ b,
                                                __hip_bfloat16* __restrict__ wtb) {
    int id = blockIdx.x * 256 + threadIdx.x;       // < 912*128
    int c  = id >> 7;
    int k  = id & 127;
    float v = 0.f;
    if (k < N_HIDDEN) {
        if (c < N_FEAT * N_HIDDEN) {
            int f = c / N_HIDDEN;
            int i = c - f * N_HIDDEN;
            v = W[f * (N_HIDDEN * N_HIDDEN) + i * N_HIDDEN + k];
        } else if (c < (N_FEAT + 1) * N_HIDDEN) {
            int i = c - N_FEAT * N_HIDDEN;
            v = b[i * N_HIDDEN + k];
        }
    }
    wtb[id] = __float2bfloat16(v);
}

// ---- GEMM: U[a][c] = sum_k afb[a][k] * wtb[c][k], bf16 MFMA, U stored bf16
__global__ __launch_bounds__(256) void gemm_u(const __hip_bfloat16* __restrict__ afb,
                                              const __hip_bfloat16* __restrict__ wtb,
                                              __hip_bfloat16* __restrict__ u) {
    int wave = threadIdx.x >> 6;
    int lane = threadIdx.x & 63;
    int quad = lane >> 4;
    int l15  = lane & 15;
    int m0   = (blockIdx.x * 4 + wave) * 16;       // row tile base, < 16000

    const __hip_bfloat16* ap = afb + (m0 + l15) * KP + quad * 8;
    bf16x8_t a0 = *(const bf16x8_t*)(ap);
    bf16x8_t a1 = *(const bf16x8_t*)(ap + 32);
    bf16x8_t a2 = *(const bf16x8_t*)(ap + 64);
    bf16x8_t a3 = *(const bf16x8_t*)(ap + 96);

    int nt0 = blockIdx.y * 19;
    for (int nt = nt0; nt < nt0 + 19; ++nt) {
        int c = nt * 16 + l15;
        const __hip_bfloat16* bp = wtb + c * KP + quad * 8;
        bf16x8_t b0 = *(const bf16x8_t*)(bp);
        bf16x8_t b1 = *(const bf16x8_t*)(bp + 32);
        bf16x8_t b2 = *(const bf16x8_t*)(bp + 64);
        bf16x8_t b3 = *(const bf16x8_t*)(bp + 96);
        f32x4_t acc = {0.f, 0.f, 0.f, 0.f};
        acc = __builtin_amdgcn_mfma_f32_16x16x32_bf16(a0, b0, acc, 0, 0, 0);
        acc = __builtin_amdgcn_mfma_f32_16x16x32_bf16(a1, b1, acc, 0, 0, 0);
        acc = __builtin_amdgcn_mfma_f32_16x16x32_bf16(a2, b2, acc, 0, 0, 0);
        acc = __builtin_amdgcn_mfma_f32_16x16x32_bf16(a3, b3, acc, 0, 0, 0);
#pragma unroll
        for (int r = 0; r < 4; ++r) {
            int rr = m0 + quad * 4 + r;
            u[rr * SU + c] = __float2bfloat16(acc[r]);
        }
    }
}

// ---- histogram + bucket: group edge ids by dest atom (no scan needed)
__global__ __launch_bounds__(256) void hist_bucket(const int* __restrict__ a2p,
                                                   int* __restrict__ deg,
                                                   int* __restrict__ bucket) {
    int e = blockIdx.x * 256 + threadIdx.x;
    if (e >= N_PAIRS) return;
    int dest = a2p[e * 2];
    int slot = atomicAdd(&deg[dest], 1);
    if (slot < MAX_DEG) bucket[dest * MAX_DEG + slot] = e;
}

// ---- accumulate: one wave per dest atom; register accumulation, no atomics.
//      out[d,i] = sum_{e in bucket[d]} ( U[src_e,800+i] + sum_f pf[e,f]*U[src_e,f*100+i] )
__global__ __launch_bounds__(256) void accum_kernel(const float* __restrict__ pf,
                                                    const int* __restrict__ a2p,
                                                    const __hip_bfloat16* __restrict__ u,
                                                    const int* __restrict__ deg,
                                                    const int* __restrict__ bucket,
                                                    float* __restrict__ out) {
    int d    = blockIdx.x * 4 + (threadIdx.x >> 6);   // dest atom, < 16000
    int lane = threadIdx.x & 63;
    int i0   = lane * 2;                              // this lane covers i0, i0+1
    bool act = (i0 < N_HIDDEN);

    int n = deg[d];                                   // wave-uniform
    if (n > MAX_DEG) n = MAX_DEG;

    // prefetch edge ids and src atoms by lane, broadcast via shfl later
    int e_l = 0, src_l = 0;
    if (lane < n) {
        e_l   = bucket[d * MAX_DEG + lane];
        src_l = a2p[e_l * 2 + 1];
    }

    float acc0 = 0.f, acc1 = 0.f;
    for (int t = 0; t < n; ++t) {
        int e   = __shfl(e_l, t, 64);
        int src = __shfl(src_l, t, 64);
        const __hip_bfloat16* ur = u + src * SU;
        const float* pfe = pf + e * N_FEAT;
        float4 p0 = *(const float4*)(pfe);            // uniform address -> broadcast
        float4 p1 = *(const float4*)(pfe + 4);
        if (act) {
            __hip_bfloat162 bb = *(const __hip_bfloat162*)(ur + N_FEAT * N_HIDDEN + i0);
            acc0 += __bfloat162float(bb.x);
            acc1 += __bfloat162float(bb.y);
            float pv[8] = {p0.x, p0.y, p0.z, p0.w, p1.x, p1.y, p1.z, p1.w};
#pragma unroll
            for (int f = 0; f < N_FEAT; ++f) {
                __hip_bfloat162 uu = *(const __hip_bfloat162*)(ur + f * N_HIDDEN + i0);
                acc0 += pv[f] * __bfloat162float(uu.x);
                acc1 += pv[f] * __bfloat162float(uu.y);
            }
        }
    }
    if (act) {
        float2 o = {acc0, acc1};
        *(float2*)(out + d * N_HIDDEN + i0) = o;      // covers all rows, incl. deg==0
    }
}

extern "C" void kernel_launch(void* const* d_in, const int* in_sizes, int n_in,
                              void* d_out, int out_size, void* d_ws, size_t ws_size,
                              hipStream_t stream) {
    const float* pf  = (const float*)d_in[0];   // (64000, 8)
    const float* af  = (const float*)d_in[1];   // (16000, 100)
    const int*   a2p = (const int*)d_in[2];     // (64000, 2)
    const float* W   = (const float*)d_in[3];   // (8, 10000)
    const float* b   = (const float*)d_in[4];   // (10000,)
    float* out = (float*)d_out;                 // (16000, 100) fp32

    char* ws = (char*)d_ws;
    __hip_bfloat16* afb = (__hip_bfloat16*)ws;                        // 4,096,000 B
    __hip_bfloat16* wtb = (__hip_bfloat16*)(ws + 4096000);            //   233,472 B
    __hip_bfloat16* u   = (__hip_bfloat16*)(ws + 4096000 + 233472);   // 29,184,000 B
    int* deg    = (int*)(ws + 4096000 + 233472 + 29184000);           //    64,000 B
    int* bucket = (int*)(ws + 4096000 + 233472 + 29184000 + 64000);   // 4,096,000 B

    hipMemsetAsync(deg, 0, N_ATOMS * sizeof(int), stream);
    prep_afb<<<(N_ATOMS * KP) / 256, 256, 0, stream>>>(af, afb);
    prep_wtb<<<(SU * KP) / 256, 256, 0, stream>>>(W, b, wtb);
    gemm_u<<<dim3(N_ATOMS / 64, 3), 256, 0, stream>>>(afb, wtb, u);
    hist_bucket<<<(N_PAIRS + 255) / 256, 256, 0, stream>>>(a2p, deg, bucket);
    accum_kernel<<<N_ATOMS / 4, 256, 0, stream>>>(pf, a2p, u, deg, bucket, out);
}